// Round 1
// baseline (965.350 us; speedup 1.0000x reference)
//
#include <hip/hip_runtime.h>
#include <hip/hip_bf16.h>
#include <cstdint>
#include <cstddef>

// ---------------------------------------------------------------------------
// MoE layer, sparse top-2 formulation.
//   gate = softmax(x@Wg+bg); top2 renorm
//   out  = x + sum_k w_k * ( gelu(x@W1[ek]+b1[ek]) @ W2[ek] + b2[ek] )
// Tokens grouped per expert into 128-aligned regions; two grouped bf16 MFMA
// GEMMs (128x128xBK64 tiles, global_load_lds + XOR-swizzled LDS).
// ---------------------------------------------------------------------------

#define N_TOK 16384
#define DIM   1024
#define NEXP  8
#define HID   2048
#define CAP   (2*N_TOK + NEXP*128)   /* 33792 rows incl. per-expert pad */
#define CHUNK_TILES 66
#define CHUNK_ROWS  (CHUNK_TILES*128) /* 8448 */
#define NCHUNK 4

typedef short  bf16x8 __attribute__((ext_vector_type(8)));
typedef float  f32x4  __attribute__((ext_vector_type(4)));

__device__ __forceinline__ unsigned short f2bf(float f) {
  union { float f; unsigned u; } v; v.f = f;
  unsigned r = v.u + 0x7fffu + ((v.u >> 16) & 1u);   // RNE
  return (unsigned short)(r >> 16);
}

#define GLOAD_LDS16(gp, lp)                                                    \
  __builtin_amdgcn_global_load_lds(                                            \
      (const __attribute__((address_space(1))) void*)(gp),                     \
      (__attribute__((address_space(3))) void*)(lp), 16, 0, 0)

// ---------------- conversions -------------------------------------------------
// x fp32 -> xb bf16, and out = x (residual init)
__global__ void convert_x_kernel(const float* __restrict__ x,
                                 unsigned short* __restrict__ xb,
                                 float* __restrict__ out) {
  size_t i = (size_t)blockIdx.x * 256 + threadIdx.x;   // over N*D/4 float4s
  float4 v = ((const float4*)x)[i];
  ((float4*)out)[i] = v;
  ushort4 o;
  o.x = f2bf(v.x); o.y = f2bf(v.y); o.z = f2bf(v.z); o.w = f2bf(v.w);
  ((ushort4*)xb)[i] = o;
}

// src [E][R][C] fp32  ->  dst [E][C][R] bf16 (per-expert transpose)
__global__ void transpose_kernel(const float* __restrict__ src,
                                 unsigned short* __restrict__ dst,
                                 int R, int C) {
  __shared__ float tile[32][33];
  int e = blockIdx.z;
  int rb = blockIdx.y * 32, cb = blockIdx.x * 32;
  int tx = threadIdx.x & 31, ty = threadIdx.x >> 5;   // ty 0..7
  const float* s = src + ((size_t)e * R + rb) * C + cb;
#pragma unroll
  for (int i = 0; i < 4; ++i)
    tile[ty + i*8][tx] = s[(size_t)(ty + i*8) * C + tx];
  __syncthreads();
  unsigned short* d = dst + ((size_t)e * C + cb) * R + rb;
#pragma unroll
  for (int i = 0; i < 4; ++i) {
    int r2 = ty + i*8;
    d[(size_t)r2 * R + tx] = f2bf(tile[tx][r2]);
  }
}

// ---------------- gating -----------------------------------------------------
// one wave per token: logits, softmax, top2, renorm weights
__global__ void gating_kernel(const float* __restrict__ x,
                              const float* __restrict__ Wg,
                              const float* __restrict__ bg,
                              int* __restrict__ tok_ids,
                              float* __restrict__ tok_w) {
  int wid  = threadIdx.x >> 6;
  int lane = threadIdx.x & 63;
  int t = blockIdx.x * 4 + wid;
  const float* xr = x + (size_t)t * DIM;
  float acc[NEXP];
#pragma unroll
  for (int e = 0; e < NEXP; ++e) acc[e] = 0.f;
#pragma unroll
  for (int i = 0; i < 4; ++i) {
    int d0 = i * 256 + lane * 4;
    float4 xv = *(const float4*)(xr + d0);
    const float* wr = Wg + (size_t)d0 * NEXP;
#pragma unroll
    for (int j = 0; j < 4; ++j) {
      float xs = (j == 0) ? xv.x : (j == 1) ? xv.y : (j == 2) ? xv.z : xv.w;
      float4 wa = *(const float4*)(wr + j * NEXP);
      float4 wb = *(const float4*)(wr + j * NEXP + 4);
      acc[0] += xs * wa.x; acc[1] += xs * wa.y; acc[2] += xs * wa.z; acc[3] += xs * wa.w;
      acc[4] += xs * wb.x; acc[5] += xs * wb.y; acc[6] += xs * wb.z; acc[7] += xs * wb.w;
    }
  }
#pragma unroll
  for (int off = 32; off >= 1; off >>= 1)
#pragma unroll
    for (int e = 0; e < NEXP; ++e)
      acc[e] += __shfl_xor(acc[e], off, 64);
  if (lane == 0) {
#pragma unroll
    for (int e = 0; e < NEXP; ++e) acc[e] += bg[e];
    float m = acc[0];
#pragma unroll
    for (int e = 1; e < NEXP; ++e) m = fmaxf(m, acc[e]);
    float p[NEXP];
#pragma unroll
    for (int e = 0; e < NEXP; ++e) p[e] = expf(acc[e] - m);
    int i0 = 0; float v0 = p[0];
#pragma unroll
    for (int e = 1; e < NEXP; ++e) if (p[e] > v0) { v0 = p[e]; i0 = e; }
    int i1 = -1; float v1 = -1.f;
#pragma unroll
    for (int e = 0; e < NEXP; ++e) if (e != i0 && p[e] > v1) { v1 = p[e]; i1 = e; }
    float s = v0 + v1;
    tok_ids[t*2]     = i0;  tok_ids[t*2 + 1] = i1;
    tok_w[t*2]       = v0 / s;  tok_w[t*2 + 1] = v1 / s;
  }
}

// per-expert counts (no atomics: one block per expert reduces)
__global__ void hist_kernel(const int* __restrict__ tok_ids, int* __restrict__ meta) {
  __shared__ int red[256];
  int e = blockIdx.x;
  int c = 0;
  for (int i = threadIdx.x; i < 2 * N_TOK; i += 256) c += (tok_ids[i] == e) ? 1 : 0;
  red[threadIdx.x] = c;
  __syncthreads();
  for (int s = 128; s > 0; s >>= 1) {
    if (threadIdx.x < s) red[threadIdx.x] += red[threadIdx.x + s];
    __syncthreads();
  }
  if (threadIdx.x == 0) meta[e] = red[0];
}

// meta: [0..7]=counts  [8..16]=offsets (9, 128-aligned regions, [16]=total)
//       [17..24]=fill positions
__global__ void offsets_kernel(int* meta) {
  if (threadIdx.x == 0 && blockIdx.x == 0) {
    int off = 0;
    for (int e = 0; e < NEXP; ++e) {
      meta[8 + e]  = off;
      meta[17 + e] = off;
      off += (meta[e] + 127) & ~127;
    }
    meta[16] = off;
  }
}

__global__ void filldef_kernel(int* __restrict__ list_token, float* __restrict__ list_w) {
  int i = blockIdx.x * 256 + threadIdx.x;
  if (i < CAP) { list_token[i] = 0; list_w[i] = 0.f; }
}

// scatter (token,slot) into per-expert regions; wave-aggregated atomics
__global__ void scatter_kernel(const int* __restrict__ tok_ids,
                               const float* __restrict__ tok_w,
                               int* __restrict__ meta,
                               int* __restrict__ list_token,
                               float* __restrict__ list_w) {
  int idx  = blockIdx.x * 256 + threadIdx.x;   // 0..2N-1
  int lane = threadIdx.x & 63;
  int e = tok_ids[idx];
  float w = tok_w[idx];
  int pos = 0;
#pragma unroll 1
  for (int ee = 0; ee < NEXP; ++ee) {
    bool mine = (e == ee);
    unsigned long long mask = __ballot(mine);
    if (mask) {
      int leader = __ffsll((unsigned long long)mask) - 1;
      int cnt = (int)__popcll(mask);
      int base = 0;
      if (lane == leader) base = atomicAdd(&meta[17 + ee], cnt);
      base = __shfl(base, leader, 64);
      if (mine) pos = base + (int)__popcll(mask & ((1ull << lane) - 1ull));
    }
  }
  list_token[pos] = idx >> 1;
  list_w[pos]     = w;
}

// ---------------- grouped GEMMs ----------------------------------------------
// 128x128 tile, BK=64, 4 waves (2x2), 16x16x32 bf16 MFMA, 4x4 frags/wave.
// LDS XOR swizzle: element (row,k0) lives at short idx (row*64+k0)^((row&7)<<3).
// global_load_lds writes linearly; source address pre-swizzled to compensate.

__global__ void gemm1_kernel(const unsigned short* __restrict__ xb,   // [N][D]
                             const unsigned short* __restrict__ w1t,  // [E][H][D]
                             const float* __restrict__ b1,            // [E][H]
                             const int* __restrict__ meta,
                             const int* __restrict__ list_token,
                             unsigned short* __restrict__ hb,         // [CHUNK][H]
                             int chunk_base) {
  const int tid = threadIdx.x, lane = tid & 63;
  const int wid = tid >> 6, wr = wid >> 1, wc = wid & 1;
  const int bx = blockIdx.x, by = blockIdx.y;
  const int r0 = chunk_base + by * 128;
  const int* offs = meta + 8;
  if (r0 >= offs[8]) return;
  int e = 0;
#pragma unroll
  for (int k = 1; k < NEXP; ++k) if (r0 >= offs[k]) e = k;

  __shared__ __align__(16) unsigned short As[128 * 64];
  __shared__ __align__(16) unsigned short Bs[128 * 64];

  f32x4 acc[4][4] = {};

  const unsigned short* bsrc = w1t + ((size_t)e * HID + (size_t)bx * 128) * DIM;
  int lrow[4], lk0[4];
  const unsigned short* arow[4];
#pragma unroll
  for (int i = 0; i < 4; ++i) {
    int g = i * 256 + tid;
    int row = g >> 3, u = g & 7;
    lrow[i] = row;
    lk0[i]  = ((u ^ (row & 7)) << 3);
    arow[i] = xb + (size_t)list_token[r0 + row] * DIM;
  }
  const int llo = lane & 15, lhi = lane >> 4;

  for (int kt = 0; kt < DIM / 64; ++kt) {
    __syncthreads();
#pragma unroll
    for (int i = 0; i < 4; ++i) {
      int g4 = (i * 256 + (tid & ~63)) * 8;   // wave-uniform LDS short offset
      GLOAD_LDS16(arow[i] + kt * 64 + lk0[i], &As[g4]);
      GLOAD_LDS16(bsrc + (size_t)lrow[i] * DIM + kt * 64 + lk0[i], &Bs[g4]);
    }
    __syncthreads();
    bf16x8 af[4][2], bfr[4][2];
#pragma unroll
    for (int m = 0; m < 4; ++m)
#pragma unroll
      for (int kk = 0; kk < 2; ++kk) {
        int ra = wr * 64 + m * 16 + llo;
        af[m][kk]  = *(const bf16x8*)&As[(ra * 64 + kk * 32 + lhi * 8) ^ ((llo & 7) << 3)];
        int rb = wc * 64 + m * 16 + llo;
        bfr[m][kk] = *(const bf16x8*)&Bs[(rb * 64 + kk * 32 + lhi * 8) ^ ((llo & 7) << 3)];
      }
#pragma unroll
    for (int kk = 0; kk < 2; ++kk)
#pragma unroll
      for (int m = 0; m < 4; ++m)
#pragma unroll
        for (int n = 0; n < 4; ++n)
          acc[m][n] = __builtin_amdgcn_mfma_f32_16x16x32_bf16(af[m][kk], bfr[n][kk], acc[m][n], 0, 0, 0);
  }

  const float* b1e = b1 + (size_t)e * HID + bx * 128;
#pragma unroll
  for (int m = 0; m < 4; ++m)
#pragma unroll
    for (int n = 0; n < 4; ++n)
#pragma unroll
      for (int j = 0; j < 4; ++j) {
        int rl = wr * 64 + m * 16 + lhi * 4 + j;
        int cl = wc * 64 + n * 16 + llo;
        float v = acc[m][n][j] + b1e[cl];
        v = 0.5f * v * (1.0f + erff(v * 0.70710678118f));   // exact gelu
        hb[(size_t)(by * 128 + rl) * HID + bx * 128 + cl] = f2bf(v);
      }
}

__global__ void gemm2_kernel(const unsigned short* __restrict__ hb,   // [CHUNK][H]
                             const unsigned short* __restrict__ w2t,  // [E][D][H]
                             const float* __restrict__ b2,            // [E][D]
                             const int* __restrict__ meta,
                             const int* __restrict__ list_token,
                             const float* __restrict__ list_w,
                             float* __restrict__ out,
                             int chunk_base) {
  const int tid = threadIdx.x, lane = tid & 63;
  const int wid = tid >> 6, wr = wid >> 1, wc = wid & 1;
  const int bx = blockIdx.x, by = blockIdx.y;
  const int r0 = chunk_base + by * 128;
  const int* offs = meta + 8;
  if (r0 >= offs[8]) return;
  int e = 0;
#pragma unroll
  for (int k = 1; k < NEXP; ++k) if (r0 >= offs[k]) e = k;

  __shared__ __align__(16) unsigned short As[128 * 64];
  __shared__ __align__(16) unsigned short Bs[128 * 64];

  f32x4 acc[4][4] = {};

  const unsigned short* bsrc = w2t + ((size_t)e * DIM + (size_t)bx * 128) * HID;
  int lrow[4], lk0[4];
  const unsigned short* arow[4];
#pragma unroll
  for (int i = 0; i < 4; ++i) {
    int g = i * 256 + tid;
    int row = g >> 3, u = g & 7;
    lrow[i] = row;
    lk0[i]  = ((u ^ (row & 7)) << 3);
    arow[i] = hb + (size_t)(by * 128 + row) * HID;
  }
  const int llo = lane & 15, lhi = lane >> 4;

  for (int kt = 0; kt < HID / 64; ++kt) {
    __syncthreads();
#pragma unroll
    for (int i = 0; i < 4; ++i) {
      int g4 = (i * 256 + (tid & ~63)) * 8;
      GLOAD_LDS16(arow[i] + kt * 64 + lk0[i], &As[g4]);
      GLOAD_LDS16(bsrc + (size_t)lrow[i] * HID + kt * 64 + lk0[i], &Bs[g4]);
    }
    __syncthreads();
    bf16x8 af[4][2], bfr[4][2];
#pragma unroll
    for (int m = 0; m < 4; ++m)
#pragma unroll
      for (int kk = 0; kk < 2; ++kk) {
        int ra = wr * 64 + m * 16 + llo;
        af[m][kk]  = *(const bf16x8*)&As[(ra * 64 + kk * 32 + lhi * 8) ^ ((llo & 7) << 3)];
        int rb = wc * 64 + m * 16 + llo;
        bfr[m][kk] = *(const bf16x8*)&Bs[(rb * 64 + kk * 32 + lhi * 8) ^ ((llo & 7) << 3)];
      }
#pragma unroll
    for (int kk = 0; kk < 2; ++kk)
#pragma unroll
      for (int m = 0; m < 4; ++m)
#pragma unroll
        for (int n = 0; n < 4; ++n)
          acc[m][n] = __builtin_amdgcn_mfma_f32_16x16x32_bf16(af[m][kk], bfr[n][kk], acc[m][n], 0, 0, 0);
  }

  const float* b2e = b2 + (size_t)e * DIM + bx * 128;
#pragma unroll
  for (int m = 0; m < 4; ++m)
#pragma unroll
    for (int n = 0; n < 4; ++n)
#pragma unroll
      for (int j = 0; j < 4; ++j) {
        int rl = wr * 64 + m * 16 + lhi * 4 + j;
        int cl = wc * 64 + n * 16 + llo;
        int rg = r0 + rl;
        float v = acc[m][n][j] + b2e[cl];
        float w = list_w[rg];
        atomicAdd(&out[(size_t)list_token[rg] * DIM + bx * 128 + cl], w * v);
      }
}

// ---------------- launch ------------------------------------------------------
extern "C" void kernel_launch(void* const* d_in, const int* in_sizes, int n_in,
                              void* d_out, int out_size, void* d_ws, size_t ws_size,
                              hipStream_t stream) {
  const float* x  = (const float*)d_in[0];
  const float* Wg = (const float*)d_in[1];
  const float* bg = (const float*)d_in[2];
  const float* W1 = (const float*)d_in[3];
  const float* b1 = (const float*)d_in[4];
  const float* W2 = (const float*)d_in[5];
  const float* b2 = (const float*)d_in[6];
  float* out = (float*)d_out;

  char* ws = (char*)d_ws;
  size_t off = 0;
  auto alloc = [&](size_t bytes) -> void* {
    void* p = ws + off;
    off = (off + bytes + 255) & ~(size_t)255;
    return p;
  };
  unsigned short* xb   = (unsigned short*)alloc((size_t)N_TOK * DIM * 2);
  unsigned short* w1t  = (unsigned short*)alloc((size_t)NEXP * HID * DIM * 2);
  unsigned short* w2t  = (unsigned short*)alloc((size_t)NEXP * DIM * HID * 2);
  unsigned short* hb   = (unsigned short*)alloc((size_t)CHUNK_ROWS * HID * 2);
  int*   tok_ids    = (int*)alloc((size_t)N_TOK * 2 * 4);
  float* tok_w      = (float*)alloc((size_t)N_TOK * 2 * 4);
  int*   list_token = (int*)alloc((size_t)CAP * 4);
  float* list_w     = (float*)alloc((size_t)CAP * 4);
  int*   meta       = (int*)alloc(256);

  // conversions (also initializes out = x for the residual)
  convert_x_kernel<<<(N_TOK * DIM / 4) / 256, 256, 0, stream>>>(x, xb, out);
  transpose_kernel<<<dim3(HID / 32, DIM / 32, NEXP), 256, 0, stream>>>(W1, w1t, DIM, HID);
  transpose_kernel<<<dim3(DIM / 32, HID / 32, NEXP), 256, 0, stream>>>(W2, w2t, HID, DIM);

  // gating + grouping
  gating_kernel<<<N_TOK / 4, 256, 0, stream>>>(x, Wg, bg, tok_ids, tok_w);
  hist_kernel<<<NEXP, 256, 0, stream>>>(tok_ids, meta);
  offsets_kernel<<<1, 64, 0, stream>>>(meta);
  filldef_kernel<<<(CAP + 255) / 256, 256, 0, stream>>>(list_token, list_w);
  scatter_kernel<<<(2 * N_TOK) / 256, 256, 0, stream>>>(tok_ids, tok_w, meta, list_token, list_w);

  // grouped expert MLP, h chunked to bound workspace
  for (int c = 0; c < NCHUNK; ++c) {
    gemm1_kernel<<<dim3(HID / 128, CHUNK_TILES), 256, 0, stream>>>(
        xb, w1t, b1, meta, list_token, hb, c * CHUNK_ROWS);
    gemm2_kernel<<<dim3(DIM / 128, CHUNK_TILES), 256, 0, stream>>>(
        hb, w2t, b2, meta, list_token, list_w, out, c * CHUNK_ROWS);
  }
}

// Round 2
// 774.782 us; speedup vs baseline: 1.2460x; 1.2460x over previous
//
#include <hip/hip_runtime.h>
#include <hip/hip_bf16.h>
#include <cstdint>
#include <cstddef>

// ---------------------------------------------------------------------------
// MoE layer, sparse top-2 formulation.
//   gate = softmax(x@Wg+bg); top2 renorm
//   out  = x + sum_k w_k * ( gelu(x@W1[ek]+b1[ek]) @ W2[ek] + b2[ek] )
// Tokens grouped per expert into 128-aligned regions; two grouped bf16 MFMA
// GEMMs (128x128xBK64 tiles, global_load_lds + XOR-swizzled LDS).
// R2: dynamic de-chunking (grid parallelism), XCD-aware block swizzle,
//     convert fused into gating.
// ---------------------------------------------------------------------------

#define N_TOK 16384
#define DIM   1024
#define NEXP  8
#define HID   2048
#define CAP   (2*N_TOK + NEXP*128)   /* 33792 rows incl. per-expert pad */
#define TOT_TILES (CAP/128)          /* 264 row-tiles */

typedef short  bf16x8 __attribute__((ext_vector_type(8)));
typedef float  f32x4  __attribute__((ext_vector_type(4)));

__device__ __forceinline__ unsigned short f2bf(float f) {
  union { float f; unsigned u; } v; v.f = f;
  unsigned r = v.u + 0x7fffu + ((v.u >> 16) & 1u);   // RNE
  return (unsigned short)(r >> 16);
}

#define GLOAD_LDS16(gp, lp)                                                    \
  __builtin_amdgcn_global_load_lds(                                            \
      (const __attribute__((address_space(1))) void*)(gp),                     \
      (__attribute__((address_space(3))) void*)(lp), 16, 0, 0)

// ---------------- transposes -------------------------------------------------
// src [E][R][C] fp32  ->  dst [E][C][R] bf16 (per-expert transpose)
__global__ void transpose_kernel(const float* __restrict__ src,
                                 unsigned short* __restrict__ dst,
                                 int R, int C) {
  __shared__ float tile[32][33];
  int e = blockIdx.z;
  int rb = blockIdx.y * 32, cb = blockIdx.x * 32;
  int tx = threadIdx.x & 31, ty = threadIdx.x >> 5;   // ty 0..7
  const float* s = src + ((size_t)e * R + rb) * C + cb;
#pragma unroll
  for (int i = 0; i < 4; ++i)
    tile[ty + i*8][tx] = s[(size_t)(ty + i*8) * C + tx];
  __syncthreads();
  unsigned short* d = dst + ((size_t)e * C + cb) * R + rb;
#pragma unroll
  for (int i = 0; i < 4; ++i) {
    int r2 = ty + i*8;
    d[(size_t)r2 * R + tx] = f2bf(tile[tx][r2]);
  }
}

// ---------------- gating (+ fused convert / residual-init) ------------------
// one wave per token: logits, softmax, top2, renorm weights.
// While streaming x, also emit xb = bf16(x) and out = x.
__global__ void gating_kernel(const float* __restrict__ x,
                              const float* __restrict__ Wg,
                              const float* __restrict__ bg,
                              unsigned short* __restrict__ xb,
                              float* __restrict__ out,
                              int* __restrict__ tok_ids,
                              float* __restrict__ tok_w) {
  int wid  = threadIdx.x >> 6;
  int lane = threadIdx.x & 63;
  int t = blockIdx.x * 4 + wid;
  const float* xr = x + (size_t)t * DIM;
  float4* outr = (float4*)(out + (size_t)t * DIM);
  ushort4* xbr = (ushort4*)(xb + (size_t)t * DIM);
  float acc[NEXP];
#pragma unroll
  for (int e = 0; e < NEXP; ++e) acc[e] = 0.f;
#pragma unroll
  for (int i = 0; i < 4; ++i) {
    int d0 = i * 256 + lane * 4;
    float4 xv = *(const float4*)(xr + d0);
    outr[i * 64 + lane] = xv;                      // residual init
    ushort4 o;
    o.x = f2bf(xv.x); o.y = f2bf(xv.y); o.z = f2bf(xv.z); o.w = f2bf(xv.w);
    xbr[i * 64 + lane] = o;                        // bf16 copy for GEMM A
    const float* wr = Wg + (size_t)d0 * NEXP;
#pragma unroll
    for (int j = 0; j < 4; ++j) {
      float xs = (j == 0) ? xv.x : (j == 1) ? xv.y : (j == 2) ? xv.z : xv.w;
      float4 wa = *(const float4*)(wr + j * NEXP);
      float4 wb = *(const float4*)(wr + j * NEXP + 4);
      acc[0] += xs * wa.x; acc[1] += xs * wa.y; acc[2] += xs * wa.z; acc[3] += xs * wa.w;
      acc[4] += xs * wb.x; acc[5] += xs * wb.y; acc[6] += xs * wb.z; acc[7] += xs * wb.w;
    }
  }
#pragma unroll
  for (int off = 32; off >= 1; off >>= 1)
#pragma unroll
    for (int e = 0; e < NEXP; ++e)
      acc[e] += __shfl_xor(acc[e], off, 64);
  if (lane == 0) {
#pragma unroll
    for (int e = 0; e < NEXP; ++e) acc[e] += bg[e];
    float m = acc[0];
#pragma unroll
    for (int e = 1; e < NEXP; ++e) m = fmaxf(m, acc[e]);
    float p[NEXP];
#pragma unroll
    for (int e = 0; e < NEXP; ++e) p[e] = expf(acc[e] - m);
    int i0 = 0; float v0 = p[0];
#pragma unroll
    for (int e = 1; e < NEXP; ++e) if (p[e] > v0) { v0 = p[e]; i0 = e; }
    int i1 = -1; float v1 = -1.f;
#pragma unroll
    for (int e = 0; e < NEXP; ++e) if (e != i0 && p[e] > v1) { v1 = p[e]; i1 = e; }
    float s = v0 + v1;
    tok_ids[t*2]     = i0;  tok_ids[t*2 + 1] = i1;
    tok_w[t*2]       = v0 / s;  tok_w[t*2 + 1] = v1 / s;
  }
}

// per-expert counts (no atomics: one block per expert reduces)
__global__ void hist_kernel(const int* __restrict__ tok_ids, int* __restrict__ meta) {
  __shared__ int red[256];
  int e = blockIdx.x;
  int c = 0;
  for (int i = threadIdx.x; i < 2 * N_TOK; i += 256) c += (tok_ids[i] == e) ? 1 : 0;
  red[threadIdx.x] = c;
  __syncthreads();
  for (int s = 128; s > 0; s >>= 1) {
    if (threadIdx.x < s) red[threadIdx.x] += red[threadIdx.x + s];
    __syncthreads();
  }
  if (threadIdx.x == 0) meta[e] = red[0];
}

// meta: [0..7]=counts  [8..16]=offsets (9, 128-aligned regions, [16]=total)
//       [17..24]=fill positions
__global__ void offsets_kernel(int* meta) {
  if (threadIdx.x == 0 && blockIdx.x == 0) {
    int off = 0;
    for (int e = 0; e < NEXP; ++e) {
      meta[8 + e]  = off;
      meta[17 + e] = off;
      off += (meta[e] + 127) & ~127;
    }
    meta[16] = off;
  }
}

__global__ void filldef_kernel(int* __restrict__ list_token, float* __restrict__ list_w) {
  int i = blockIdx.x * 256 + threadIdx.x;
  if (i < CAP) { list_token[i] = 0; list_w[i] = 0.f; }
}

// scatter (token,slot) into per-expert regions; wave-aggregated atomics
__global__ void scatter_kernel(const int* __restrict__ tok_ids,
                               const float* __restrict__ tok_w,
                               int* __restrict__ meta,
                               int* __restrict__ list_token,
                               float* __restrict__ list_w) {
  int idx  = blockIdx.x * 256 + threadIdx.x;   // 0..2N-1
  int lane = threadIdx.x & 63;
  int e = tok_ids[idx];
  float w = tok_w[idx];
  int pos = 0;
#pragma unroll 1
  for (int ee = 0; ee < NEXP; ++ee) {
    bool mine = (e == ee);
    unsigned long long mask = __ballot(mine);
    if (mask) {
      int leader = __ffsll((unsigned long long)mask) - 1;
      int cnt = (int)__popcll(mask);
      int base = 0;
      if (lane == leader) base = atomicAdd(&meta[17 + ee], cnt);
      base = __shfl(base, leader, 64);
      if (mine) pos = base + (int)__popcll(mask & ((1ull << lane) - 1ull));
    }
  }
  list_token[pos] = idx >> 1;
  list_w[pos]     = w;
}

// ---------------- grouped GEMMs ----------------------------------------------
// 128x128 tile, BK=64, 4 waves (2x2), 16x16x32 bf16 MFMA, 4x4 frags/wave.
// LDS XOR swizzle: element (row,k0) lives at short idx (row*64+k0)^((row&7)<<3).
// global_load_lds writes linearly; source address pre-swizzled to compensate.
// 1-D grid, XCD-aware bijective remap (m204), bx = inner.

__device__ __forceinline__ void xcd_swizzle(int nx_log2, int base_tile,
                                            int& bx, int& by) {
  int nwg = gridDim.x;
  int wgid = blockIdx.x;
  int q = nwg >> 3, r = nwg & 7;
  int xcd = wgid & 7, loc = wgid >> 3;
  int swz = (xcd < r ? xcd * (q + 1) : r * (q + 1) + (xcd - r) * q) + loc;
  bx = swz & ((1 << nx_log2) - 1);
  by = base_tile + (swz >> nx_log2);
}

__global__ void gemm1_kernel(const unsigned short* __restrict__ xb,   // [N][D]
                             const unsigned short* __restrict__ w1t,  // [E][H][D]
                             const float* __restrict__ b1,            // [E][H]
                             const int* __restrict__ meta,
                             const int* __restrict__ list_token,
                             unsigned short* __restrict__ hb,         // [chunk][H]
                             int base_tile) {
  const int tid = threadIdx.x, lane = tid & 63;
  const int wid = tid >> 6, wr = wid >> 1, wc = wid & 1;
  int bx, by;
  xcd_swizzle(4, base_tile, bx, by);           // nx = 16
  const int r0 = by * 128;
  const int* offs = meta + 8;
  if (r0 >= offs[8]) return;
  int e = 0;
#pragma unroll
  for (int k = 1; k < NEXP; ++k) if (r0 >= offs[k]) e = k;

  __shared__ __align__(16) unsigned short As[128 * 64];
  __shared__ __align__(16) unsigned short Bs[128 * 64];

  f32x4 acc[4][4] = {};

  const unsigned short* bsrc = w1t + ((size_t)e * HID + (size_t)bx * 128) * DIM;
  int lrow[4], lk0[4];
  const unsigned short* arow[4];
#pragma unroll
  for (int i = 0; i < 4; ++i) {
    int g = i * 256 + tid;
    int row = g >> 3, u = g & 7;
    lrow[i] = row;
    lk0[i]  = ((u ^ (row & 7)) << 3);
    arow[i] = xb + (size_t)list_token[r0 + row] * DIM;
  }
  const int llo = lane & 15, lhi = lane >> 4;

  for (int kt = 0; kt < DIM / 64; ++kt) {
    __syncthreads();
#pragma unroll
    for (int i = 0; i < 4; ++i) {
      int g4 = (i * 256 + (tid & ~63)) * 8;   // wave-uniform LDS short offset
      GLOAD_LDS16(arow[i] + kt * 64 + lk0[i], &As[g4]);
      GLOAD_LDS16(bsrc + (size_t)lrow[i] * DIM + kt * 64 + lk0[i], &Bs[g4]);
    }
    __syncthreads();
    bf16x8 af[4][2], bfr[4][2];
#pragma unroll
    for (int m = 0; m < 4; ++m)
#pragma unroll
      for (int kk = 0; kk < 2; ++kk) {
        int ra = wr * 64 + m * 16 + llo;
        af[m][kk]  = *(const bf16x8*)&As[(ra * 64 + kk * 32 + lhi * 8) ^ ((llo & 7) << 3)];
        int rb = wc * 64 + m * 16 + llo;
        bfr[m][kk] = *(const bf16x8*)&Bs[(rb * 64 + kk * 32 + lhi * 8) ^ ((llo & 7) << 3)];
      }
#pragma unroll
    for (int kk = 0; kk < 2; ++kk)
#pragma unroll
      for (int m = 0; m < 4; ++m)
#pragma unroll
        for (int n = 0; n < 4; ++n)
          acc[m][n] = __builtin_amdgcn_mfma_f32_16x16x32_bf16(af[m][kk], bfr[n][kk], acc[m][n], 0, 0, 0);
  }

  const float* b1e = b1 + (size_t)e * HID + bx * 128;
#pragma unroll
  for (int m = 0; m < 4; ++m)
#pragma unroll
    for (int n = 0; n < 4; ++n)
#pragma unroll
      for (int j = 0; j < 4; ++j) {
        int rl = wr * 64 + m * 16 + lhi * 4 + j;
        int cl = wc * 64 + n * 16 + llo;
        float v = acc[m][n][j] + b1e[cl];
        v = 0.5f * v * (1.0f + erff(v * 0.70710678118f));   // exact gelu
        hb[(size_t)((by - base_tile) * 128 + rl) * HID + bx * 128 + cl] = f2bf(v);
      }
}

__global__ void gemm2_kernel(const unsigned short* __restrict__ hb,   // [chunk][H]
                             const unsigned short* __restrict__ w2t,  // [E][D][H]
                             const float* __restrict__ b2,            // [E][D]
                             const int* __restrict__ meta,
                             const int* __restrict__ list_token,
                             const float* __restrict__ list_w,
                             float* __restrict__ out,
                             int base_tile) {
  const int tid = threadIdx.x, lane = tid & 63;
  const int wid = tid >> 6, wr = wid >> 1, wc = wid & 1;
  int bx, by;
  xcd_swizzle(3, base_tile, bx, by);           // nx = 8
  const int r0 = by * 128;
  const int* offs = meta + 8;
  if (r0 >= offs[8]) return;
  int e = 0;
#pragma unroll
  for (int k = 1; k < NEXP; ++k) if (r0 >= offs[k]) e = k;

  __shared__ __align__(16) unsigned short As[128 * 64];
  __shared__ __align__(16) unsigned short Bs[128 * 64];

  f32x4 acc[4][4] = {};

  const unsigned short* bsrc = w2t + ((size_t)e * DIM + (size_t)bx * 128) * HID;
  int lrow[4], lk0[4];
  const unsigned short* arow[4];
#pragma unroll
  for (int i = 0; i < 4; ++i) {
    int g = i * 256 + tid;
    int row = g >> 3, u = g & 7;
    lrow[i] = row;
    lk0[i]  = ((u ^ (row & 7)) << 3);
    arow[i] = hb + (size_t)((by - base_tile) * 128 + row) * HID;
  }
  const int llo = lane & 15, lhi = lane >> 4;

  for (int kt = 0; kt < HID / 64; ++kt) {
    __syncthreads();
#pragma unroll
    for (int i = 0; i < 4; ++i) {
      int g4 = (i * 256 + (tid & ~63)) * 8;
      GLOAD_LDS16(arow[i] + kt * 64 + lk0[i], &As[g4]);
      GLOAD_LDS16(bsrc + (size_t)lrow[i] * HID + kt * 64 + lk0[i], &Bs[g4]);
    }
    __syncthreads();
    bf16x8 af[4][2], bfr[4][2];
#pragma unroll
    for (int m = 0; m < 4; ++m)
#pragma unroll
      for (int kk = 0; kk < 2; ++kk) {
        int ra = wr * 64 + m * 16 + llo;
        af[m][kk]  = *(const bf16x8*)&As[(ra * 64 + kk * 32 + lhi * 8) ^ ((llo & 7) << 3)];
        int rb = wc * 64 + m * 16 + llo;
        bfr[m][kk] = *(const bf16x8*)&Bs[(rb * 64 + kk * 32 + lhi * 8) ^ ((llo & 7) << 3)];
      }
#pragma unroll
    for (int kk = 0; kk < 2; ++kk)
#pragma unroll
      for (int m = 0; m < 4; ++m)
#pragma unroll
        for (int n = 0; n < 4; ++n)
          acc[m][n] = __builtin_amdgcn_mfma_f32_16x16x32_bf16(af[m][kk], bfr[n][kk], acc[m][n], 0, 0, 0);
  }

  const float* b2e = b2 + (size_t)e * DIM + bx * 128;
#pragma unroll
  for (int m = 0; m < 4; ++m)
#pragma unroll
    for (int n = 0; n < 4; ++n)
#pragma unroll
      for (int j = 0; j < 4; ++j) {
        int rl = wr * 64 + m * 16 + lhi * 4 + j;
        int cl = wc * 64 + n * 16 + llo;
        int rg = r0 + rl;
        float v = acc[m][n][j] + b2e[cl];
        float w = list_w[rg];
        atomicAdd(&out[(size_t)list_token[rg] * DIM + bx * 128 + cl], w * v);
      }
}

// ---------------- launch ------------------------------------------------------
extern "C" void kernel_launch(void* const* d_in, const int* in_sizes, int n_in,
                              void* d_out, int out_size, void* d_ws, size_t ws_size,
                              hipStream_t stream) {
  const float* x  = (const float*)d_in[0];
  const float* Wg = (const float*)d_in[1];
  const float* bg = (const float*)d_in[2];
  const float* W1 = (const float*)d_in[3];
  const float* b1 = (const float*)d_in[4];
  const float* W2 = (const float*)d_in[5];
  const float* b2 = (const float*)d_in[6];
  float* out = (float*)d_out;

  char* ws = (char*)d_ws;
  size_t off = 0;
  auto alloc = [&](size_t bytes) -> void* {
    void* p = ws + off;
    off = (off + bytes + 255) & ~(size_t)255;
    return p;
  };
  // fixed-size buffers
  unsigned short* xb   = (unsigned short*)alloc((size_t)N_TOK * DIM * 2);
  unsigned short* w1t  = (unsigned short*)alloc((size_t)NEXP * HID * DIM * 2);
  unsigned short* w2t  = (unsigned short*)alloc((size_t)NEXP * DIM * HID * 2);
  int*   tok_ids    = (int*)alloc((size_t)N_TOK * 2 * 4);
  float* tok_w      = (float*)alloc((size_t)N_TOK * 2 * 4);
  int*   list_token = (int*)alloc((size_t)CAP * 4);
  float* list_w     = (float*)alloc((size_t)CAP * 4);
  int*   meta       = (int*)alloc(256);

  // hb gets whatever is left: pick fewest chunks that fit (1, 2, or 4).
  size_t hb_full = (size_t)CAP * HID * 2;   // 138 MB
  int nchunk = 4;
  if (ws_size - off >= hb_full + 4096)           nchunk = 1;
  else if (ws_size - off >= hb_full / 2 + 4096)  nchunk = 2;
  int tiles_per_chunk = TOT_TILES / nchunk;      // 264 / {1,2,4}
  unsigned short* hb = (unsigned short*)alloc(hb_full / nchunk);

  // gating (+ fused bf16 convert + residual init)
  gating_kernel<<<N_TOK / 4, 256, 0, stream>>>(x, Wg, bg, xb, out, tok_ids, tok_w);

  // weight transposes to bf16 [E][cols][rows]
  transpose_kernel<<<dim3(HID / 32, DIM / 32, NEXP), 256, 0, stream>>>(W1, w1t, DIM, HID);
  transpose_kernel<<<dim3(DIM / 32, HID / 32, NEXP), 256, 0, stream>>>(W2, w2t, HID, DIM);

  // grouping
  hist_kernel<<<NEXP, 256, 0, stream>>>(tok_ids, meta);
  offsets_kernel<<<1, 64, 0, stream>>>(meta);
  filldef_kernel<<<(CAP + 255) / 256, 256, 0, stream>>>(list_token, list_w);
  scatter_kernel<<<(2 * N_TOK) / 256, 256, 0, stream>>>(tok_ids, tok_w, meta, list_token, list_w);

  // grouped expert MLP
  for (int c = 0; c < nchunk; ++c) {
    gemm1_kernel<<<16 * tiles_per_chunk, 256, 0, stream>>>(
        xb, w1t, b1, meta, list_token, hb, c * tiles_per_chunk);
    gemm2_kernel<<<8 * tiles_per_chunk, 256, 0, stream>>>(
        hb, w2t, b2, meta, list_token, list_w, out, c * tiles_per_chunk);
  }
}